// Round 1
// baseline (528.887 us; speedup 1.0000x reference)
//
#include <hip/hip_runtime.h>
#include <hip/hip_bf16.h>

typedef unsigned short u16;
typedef __attribute__((ext_vector_type(8))) short short8;
typedef __attribute__((ext_vector_type(4))) float f32x4;

__device__ inline u16 f2bf(float f) {
  unsigned u = __float_as_uint(f);
  u += 0x7fffu + ((u >> 16) & 1u);   // round-to-nearest-even
  return (u16)(u >> 16);
}

// ---------------- cast fp32 -> bf16 (vectorized x4) ----------------
__global__ __launch_bounds__(256) void cast_kernel(const float* __restrict__ in,
                                                   u16* __restrict__ out, int n4) {
  int i = blockIdx.x * 256 + threadIdx.x;
  if (i >= n4) return;
  float4 v = ((const float4*)in)[i];
  ushort4 o;
  o.x = f2bf(v.x); o.y = f2bf(v.y); o.z = f2bf(v.z); o.w = f2bf(v.w);
  ((ushort4*)out)[i] = o;
}

// ---------------- transpose-cast: fp32 [K][N] -> bf16 [N][K] ----------------
__global__ __launch_bounds__(256) void tcast_kernel(const float* __restrict__ in,
                                                    u16* __restrict__ out, int K, int N) {
  __shared__ float tile[32][33];
  int bx = blockIdx.x * 32;  // N offset
  int by = blockIdx.y * 32;  // K offset
  int tx = threadIdx.x & 31, ty = threadIdx.x >> 5;
#pragma unroll
  for (int i = 0; i < 4; i++) {
    int r = ty + i * 8;
    tile[r][tx] = in[(size_t)(by + r) * N + bx + tx];
  }
  __syncthreads();
#pragma unroll
  for (int i = 0; i < 4; i++) {
    int r = ty + i * 8;
    out[(size_t)(bx + r) * K + by + tx] = f2bf(tile[tx][r]);
  }
}

// ---------------- GEMM: C[M][N] = A[M][K] * Bt[N][K]^T, bf16 MFMA ----------------
// 128x128 tile, BK=32, 4 waves of 64x64, mfma_f32_16x16x32_bf16.
// LDS rows padded to 56 elems (112B = 7*16B): b128-aligned, 2-way banks (free).
#define LDK 56

__device__ inline void cstore(float* p, float v) { *p = v; }
__device__ inline void cstore(u16* p, float v) { *p = f2bf(v); }

template <typename OutT>
__global__ __launch_bounds__(256) void gemm_bt(const u16* __restrict__ A,
                                               const u16* __restrict__ Bt,
                                               OutT* __restrict__ C,
                                               int M, int N, int K) {
  __shared__ __align__(16) u16 As[128 * LDK];
  __shared__ __align__(16) u16 Bs[128 * LDK];
  int t = threadIdx.x;
  int wave = t >> 6, lane = t & 63, l15 = lane & 15, quad = lane >> 4;
  int bn = blockIdx.x * 128, bm = blockIdx.y * 128;
  int wm = (wave >> 1) * 64, wn = (wave & 1) * 64;

  f32x4 acc[4][4];
#pragma unroll
  for (int i = 0; i < 4; i++)
#pragma unroll
    for (int j = 0; j < 4; j++) acc[i][j] = (f32x4)0.0f;

  int r0 = t >> 2, c0 = (t & 3) * 8;  // staging: 4 lanes cover one 64B row-chunk

  for (int k0 = 0; k0 < K; k0 += 32) {
    __syncthreads();
#pragma unroll
    for (int i = 0; i < 2; i++) {
      int row = i * 64 + r0;
      uint4 va = *(const uint4*)(A + (size_t)(bm + row) * K + k0 + c0);
      *(uint4*)(&As[row * LDK + c0]) = va;
      uint4 vb = *(const uint4*)(Bt + (size_t)(bn + row) * K + k0 + c0);
      *(uint4*)(&Bs[row * LDK + c0]) = vb;
    }
    __syncthreads();
    short8 a[4], b[4];
#pragma unroll
    for (int mt = 0; mt < 4; mt++)
      a[mt] = *(const short8*)(&As[(wm + mt * 16 + l15) * LDK + quad * 8]);
#pragma unroll
    for (int nt = 0; nt < 4; nt++)
      b[nt] = *(const short8*)(&Bs[(wn + nt * 16 + l15) * LDK + quad * 8]);
#pragma unroll
    for (int mt = 0; mt < 4; mt++)
#pragma unroll
      for (int nt = 0; nt < 4; nt++)
        acc[mt][nt] = __builtin_amdgcn_mfma_f32_16x16x32_bf16(a[mt], b[nt], acc[mt][nt], 0, 0, 0);
  }

  // epilogue: C/D layout row = quad*4+r, col = l15 (m89/m91-verified)
#pragma unroll
  for (int mt = 0; mt < 4; mt++)
#pragma unroll
    for (int nt = 0; nt < 4; nt++)
#pragma unroll
      for (int r = 0; r < 4; r++) {
        int row = bm + wm + mt * 16 + quad * 4 + r;
        int col = bn + wn + nt * 16 + l15;
        cstore(&C[(size_t)row * N + col], acc[mt][nt][r]);
      }
}

// ---------------- flash attention ----------------
// block = (b, h, 64-query tile); 4 waves x 16 q-rows; key tiles of 64.
// qkv layout [B*S][3072]: Q at col h*64, K at 1024+h*64, V at 2048+h*64.
#define ALDS 72  // 144B row stride: b128-aligned, 2-way banks on frag reads

__global__ __launch_bounds__(256) void attn_kernel(const u16* __restrict__ qkv,
                                                   u16* __restrict__ ctx) {
  __shared__ __align__(16) u16 Qs[64 * ALDS];  // reused as P after Q frags cached
  __shared__ __align__(16) u16 Ks[64 * ALDS];
  __shared__ __align__(16) u16 Vt[64 * ALDS];  // V transposed: Vt[d][k]
  u16* Ps = Qs;

  int t = threadIdx.x;
  int wave = t >> 6, lane = t & 63, l15 = lane & 15, quad = lane >> 4;
  int qt = (int)gridDim.x - 1 - (int)blockIdx.x;  // long blocks first
  int h = blockIdx.y, b = blockIdx.z;
  int rowbase = b * 2048;
  int q0 = qt * 64;

  int r8 = t >> 3, c8 = (t & 7) * 8;

  // stage Q tile [64][64]
#pragma unroll
  for (int i = 0; i < 2; i++) {
    int r = i * 32 + r8;
    uint4 v = *(const uint4*)(qkv + (size_t)(rowbase + q0 + r) * 3072 + h * 64 + c8);
    *(uint4*)(&Qs[r * ALDS + c8]) = v;
  }
  __syncthreads();
  // A-operand frags (constant over key loop): A[m=l15][k=quad*8+j]
  short8 qa0 = *(const short8*)(&Qs[(wave * 16 + l15) * ALDS + quad * 8]);
  short8 qa1 = *(const short8*)(&Qs[(wave * 16 + l15) * ALDS + 32 + quad * 8]);

  float m_r[4], l_r[4];
  f32x4 acc[4];
#pragma unroll
  for (int r = 0; r < 4; r++) { m_r[r] = -1e30f; l_r[r] = 0.0f; }
#pragma unroll
  for (int nt = 0; nt < 4; nt++) acc[nt] = (f32x4)0.0f;

  for (int kt = 0; kt <= qt; kt++) {
    __syncthreads();
    int krow = rowbase + kt * 64;
#pragma unroll
    for (int i = 0; i < 2; i++) {
      int r = i * 32 + r8;
      const u16* src = qkv + (size_t)(krow + r) * 3072 + h * 64 + c8;
      uint4 kv = *(const uint4*)(src + 1024);
      *(uint4*)(&Ks[r * ALDS + c8]) = kv;
      uint4 vv = *(const uint4*)(src + 2048);
      union { uint4 u; u16 s[8]; } cv; cv.u = vv;
#pragma unroll
      for (int j = 0; j < 8; j++) Vt[(c8 + j) * ALDS + r] = cv.s[j];  // scatter transpose
    }
    __syncthreads();

    // S = Q K^T  (B-operand = K[key][hd], contiguous along hd)
    f32x4 s[4];
#pragma unroll
    for (int nt = 0; nt < 4; nt++) {
      s[nt] = (f32x4)0.0f;
      short8 kb0 = *(const short8*)(&Ks[(nt * 16 + l15) * ALDS + quad * 8]);
      short8 kb1 = *(const short8*)(&Ks[(nt * 16 + l15) * ALDS + 32 + quad * 8]);
      s[nt] = __builtin_amdgcn_mfma_f32_16x16x32_bf16(qa0, kb0, s[nt], 0, 0, 0);
      s[nt] = __builtin_amdgcn_mfma_f32_16x16x32_bf16(qa1, kb1, s[nt], 0, 0, 0);
    }

    // scale + causal mask (-1e30, not -inf: fully-masked strips stay NaN-free)
    int qrow = q0 + wave * 16 + quad * 4;
#pragma unroll
    for (int nt = 0; nt < 4; nt++) {
      int key = kt * 64 + nt * 16 + l15;
#pragma unroll
      for (int r = 0; r < 4; r++) {
        float sv = s[nt][r] * 0.125f;
        s[nt][r] = (key <= qrow + r) ? sv : -1e30f;
      }
    }

    // online softmax: row stats over 16-lane groups (rows = quad*4+r)
    float alpha[4], rsum[4];
#pragma unroll
    for (int r = 0; r < 4; r++) {
      float v = fmaxf(fmaxf(s[0][r], s[1][r]), fmaxf(s[2][r], s[3][r]));
#pragma unroll
      for (int off = 1; off < 16; off <<= 1) v = fmaxf(v, __shfl_xor(v, off));
      float mnew = fmaxf(m_r[r], v);
      alpha[r] = __expf(m_r[r] - mnew);
      m_r[r] = mnew;
      rsum[r] = 0.0f;
    }
#pragma unroll
    for (int nt = 0; nt < 4; nt++)
#pragma unroll
      for (int r = 0; r < 4; r++) {
        float p = __expf(s[nt][r] - m_r[r]);
        s[nt][r] = p;
        rsum[r] += p;
      }
#pragma unroll
    for (int r = 0; r < 4; r++) {
      float v = rsum[r];
#pragma unroll
      for (int off = 1; off < 16; off <<= 1) v += __shfl_xor(v, off);
      l_r[r] = l_r[r] * alpha[r] + v;
    }
#pragma unroll
    for (int nt = 0; nt < 4; nt++)
#pragma unroll
      for (int r = 0; r < 4; r++) acc[nt][r] *= alpha[r];

    // P: C-layout regs -> LDS (own 16-row strip only)
#pragma unroll
    for (int nt = 0; nt < 4; nt++)
#pragma unroll
      for (int r = 0; r < 4; r++)
        Ps[(wave * 16 + quad * 4 + r) * ALDS + nt * 16 + l15] = f2bf(s[nt][r]);
    __syncthreads();  // uniform; orders P write->read (cross-lane via LDS)

    // O += P V   (A = P from LDS, B = V^T: contiguous along k)
    short8 pa0 = *(const short8*)(&Ps[(wave * 16 + l15) * ALDS + quad * 8]);
    short8 pa1 = *(const short8*)(&Ps[(wave * 16 + l15) * ALDS + 32 + quad * 8]);
#pragma unroll
    for (int nt = 0; nt < 4; nt++) {
      short8 vb0 = *(const short8*)(&Vt[(nt * 16 + l15) * ALDS + quad * 8]);
      short8 vb1 = *(const short8*)(&Vt[(nt * 16 + l15) * ALDS + 32 + quad * 8]);
      acc[nt] = __builtin_amdgcn_mfma_f32_16x16x32_bf16(pa0, vb0, acc[nt], 0, 0, 0);
      acc[nt] = __builtin_amdgcn_mfma_f32_16x16x32_bf16(pa1, vb1, acc[nt], 0, 0, 0);
    }
  }

  // epilogue: O / l -> ctx bf16 [B*S][1024]
#pragma unroll
  for (int nt = 0; nt < 4; nt++)
#pragma unroll
    for (int r = 0; r < 4; r++) {
      int row = rowbase + q0 + wave * 16 + quad * 4 + r;
      int col = h * 64 + nt * 16 + l15;
      ctx[(size_t)row * 1024 + col] = f2bf(acc[nt][r] / l_r[r]);
    }
}

// ---------------- launch ----------------
extern "C" void kernel_launch(void* const* d_in, const int* in_sizes, int n_in,
                              void* d_out, int out_size, void* d_ws, size_t ws_size,
                              hipStream_t stream) {
  const float* x      = (const float*)d_in[0];  // [4][2048][1024]
  const float* w_qkv  = (const float*)d_in[1];  // [1024][3072]
  const float* w_proj = (const float*)d_in[2];  // [1024][1024]
  float* out = (float*)d_out;                   // [4][2048][1024]

  char* ws = (char*)d_ws;
  u16* xb     = (u16*)(ws);                         // 16 MB
  u16* wqkvT  = (u16*)(ws + 16u * 1024 * 1024);     //  6 MB  [3072][1024]
  u16* wprojT = (u16*)(ws + 22u * 1024 * 1024);     //  2 MB  [1024][1024]
  u16* qkv    = (u16*)(ws + 24u * 1024 * 1024);     // 48 MB  [8192][3072]
  u16* ctx    = (u16*)(ws + 72u * 1024 * 1024);     // 16 MB  [8192][1024]

  cast_kernel<<<8192, 256, 0, stream>>>(x, xb, 8388608 / 4);
  tcast_kernel<<<dim3(96, 32), 256, 0, stream>>>(w_qkv, wqkvT, 1024, 3072);
  tcast_kernel<<<dim3(32, 32), 256, 0, stream>>>(w_proj, wprojT, 1024, 1024);

  gemm_bt<u16><<<dim3(24, 64), 256, 0, stream>>>(xb, wqkvT, qkv, 8192, 3072, 1024);
  attn_kernel<<<dim3(32, 16, 4), 256, 0, stream>>>(qkv, ctx);
  gemm_bt<float><<<dim3(8, 64), 256, 0, stream>>>(ctx, wprojT, out, 8192, 1024, 1024);
}

// Round 2
// 345.981 us; speedup vs baseline: 1.5287x; 1.5287x over previous
//
#include <hip/hip_runtime.h>
#include <hip/hip_bf16.h>

typedef unsigned short u16;
typedef __attribute__((ext_vector_type(8))) short short8;
typedef __attribute__((ext_vector_type(4))) float f32x4;
typedef __attribute__((ext_vector_type(16))) float f32x16;

__device__ inline u16 f2bf(float f) {
  unsigned u = __float_as_uint(f);
  u += 0x7fffu + ((u >> 16) & 1u);   // round-to-nearest-even
  return (u16)(u >> 16);
}

// ---------------- cast fp32 -> bf16 (vectorized x4) ----------------
__global__ __launch_bounds__(256) void cast_kernel(const float* __restrict__ in,
                                                   u16* __restrict__ out, int n4) {
  int i = blockIdx.x * 256 + threadIdx.x;
  if (i >= n4) return;
  float4 v = ((const float4*)in)[i];
  ushort4 o;
  o.x = f2bf(v.x); o.y = f2bf(v.y); o.z = f2bf(v.z); o.w = f2bf(v.w);
  ((ushort4*)out)[i] = o;
}

// ---------------- transpose-cast: fp32 [K][N] -> bf16 [N][K] ----------------
__global__ __launch_bounds__(256) void tcast_kernel(const float* __restrict__ in,
                                                    u16* __restrict__ out, int K, int N) {
  __shared__ float tile[32][33];
  int bx = blockIdx.x * 32;  // N offset
  int by = blockIdx.y * 32;  // K offset
  int tx = threadIdx.x & 31, ty = threadIdx.x >> 5;
#pragma unroll
  for (int i = 0; i < 4; i++) {
    int r = ty + i * 8;
    tile[r][tx] = in[(size_t)(by + r) * N + bx + tx];
  }
  __syncthreads();
#pragma unroll
  for (int i = 0; i < 4; i++) {
    int r = ty + i * 8;
    out[(size_t)(bx + r) * K + by + tx] = f2bf(tile[tx][r]);
  }
}

// ---------------- V transpose: qkv V-part [s][hd] -> vt [b][h][hd][S] ----------------
__global__ __launch_bounds__(256) void vtrans(const u16* __restrict__ qkv, u16* __restrict__ vt) {
  __shared__ __align__(16) u16 tile[64 * 72];
  int t = threadIdx.x;
  int s0 = blockIdx.x * 64, h = blockIdx.y, b = blockIdx.z;
  int bh = b * 16 + h;
#pragma unroll
  for (int i = 0; i < 2; i++) {
    int idx = i * 256 + t; int r = idx >> 3, c8 = (idx & 7) * 8;
    *(uint4*)&tile[r * 72 + c8] =
        *(const uint4*)(qkv + (size_t)(b * 2048 + s0 + r) * 3072 + 2048 + h * 64 + c8);
  }
  __syncthreads();
#pragma unroll
  for (int i = 0; i < 2; i++) {
    int idx = i * 256 + t; int hd = idx >> 3, c8 = (idx & 7) * 8;
    union { ushort s[8]; uint4 u; } pkv;
#pragma unroll
    for (int j = 0; j < 8; j++) pkv.s[j] = tile[(c8 + j) * 72 + hd];
    *(uint4*)(vt + ((size_t)bh * 64 + hd) * 2048 + s0 + c8) = pkv.u;
  }
}

// ---------------- GEMM: C[M][N] = A[M][K] * Bt[N][K]^T, m97-style ----------------
// 128x128 tile, BK=32, unpadded LDS [128][32], global_load_lds width=16.
__device__ inline void cstore(float* p, float v) { *p = v; }
__device__ inline void cstore(u16* p, float v) { *p = f2bf(v); }

template <typename OutT>
__global__ __launch_bounds__(256) void gemm_bt(const u16* __restrict__ A,
                                               const u16* __restrict__ Bt,
                                               OutT* __restrict__ Co,
                                               int M, int N, int K) {
  __shared__ __align__(16) u16 As[128 * 32];
  __shared__ __align__(16) u16 Bs[128 * 32];
  int t = threadIdx.x;
  int wave = t >> 6, lane = t & 63, l15 = lane & 15, quad = lane >> 4;
  int bn = blockIdx.x * 128, bm = blockIdx.y * 128;
  int wm = (wave >> 1) * 64, wn = (wave & 1) * 64;

  f32x4 acc[4][4];
#pragma unroll
  for (int i = 0; i < 4; i++)
#pragma unroll
    for (int j = 0; j < 4; j++) acc[i][j] = (f32x4)0.0f;

  // staging geometry: round r, wave w: LDS bytes [r*4096 + w*1024 + lane*16]
  // -> row = r*64 + w*16 + (lane>>2), col = (lane&3)*8 (elems)
  int srow = wave * 16 + (lane >> 2);
  int scol = (lane & 3) * 8;
  const u16* ga0 = A  + (size_t)(bm + srow) * K + scol;
  const u16* ga1 = A  + (size_t)(bm + 64 + srow) * K + scol;
  const u16* gb0 = Bt + (size_t)(bn + srow) * K + scol;
  const u16* gb1 = Bt + (size_t)(bn + 64 + srow) * K + scol;
  u16* lA0 = As + wave * 512;
  u16* lA1 = As + 2048 + wave * 512;
  u16* lB0 = Bs + wave * 512;
  u16* lB1 = Bs + 2048 + wave * 512;

  for (int k0 = 0; k0 < K; k0 += 32) {
    __syncthreads();
    __builtin_amdgcn_global_load_lds((const __attribute__((address_space(1))) unsigned*)(ga0 + k0),
                                     (__attribute__((address_space(3))) unsigned*)lA0, 16, 0, 0);
    __builtin_amdgcn_global_load_lds((const __attribute__((address_space(1))) unsigned*)(ga1 + k0),
                                     (__attribute__((address_space(3))) unsigned*)lA1, 16, 0, 0);
    __builtin_amdgcn_global_load_lds((const __attribute__((address_space(1))) unsigned*)(gb0 + k0),
                                     (__attribute__((address_space(3))) unsigned*)lB0, 16, 0, 0);
    __builtin_amdgcn_global_load_lds((const __attribute__((address_space(1))) unsigned*)(gb1 + k0),
                                     (__attribute__((address_space(3))) unsigned*)lB1, 16, 0, 0);
    __syncthreads();  // emits s_waitcnt vmcnt(0) before s_barrier -> LDS data valid

    short8 a[4], b[4];
#pragma unroll
    for (int mt = 0; mt < 4; mt++)
      a[mt] = *(const short8*)(&As[(wm + mt * 16 + l15) * 32 + quad * 8]);
#pragma unroll
    for (int nt = 0; nt < 4; nt++)
      b[nt] = *(const short8*)(&Bs[(wn + nt * 16 + l15) * 32 + quad * 8]);
#pragma unroll
    for (int mt = 0; mt < 4; mt++)
#pragma unroll
      for (int nt = 0; nt < 4; nt++)
        acc[mt][nt] = __builtin_amdgcn_mfma_f32_16x16x32_bf16(a[mt], b[nt], acc[mt][nt], 0, 0, 0);
  }

  // epilogue: C/D 16x16: row = quad*4+r, col = l15 (m89/m91-verified)
#pragma unroll
  for (int mt = 0; mt < 4; mt++)
#pragma unroll
    for (int nt = 0; nt < 4; nt++)
#pragma unroll
      for (int r = 0; r < 4; r++) {
        int row = bm + wm + mt * 16 + quad * 4 + r;
        int col = bn + wn + nt * 16 + l15;
        cstore(&Co[(size_t)row * N + col], acc[mt][nt][r]);
      }
}

// ---------------- flash attention, S^T formulation, 32x32x16 MFMA ----------------
// block = (qb 128 q-rows, h, b); 4 waves x 32 q; key tiles of 64.
// S^T = K*Q^T  (C/D: col=q=lane&31, row=(reg&3)+8*(reg>>2)+4*(lane>>5), m74/m101-verified)
// => softmax state (m,l) is PER-LANE. P rerouted to B-frag in registers via shfl_xor(32).
// O^T = V^T * P^T with V^T pre-transposed in global (vt).
#define KLD 72  // 144B row stride, b128-aligned

__global__ __launch_bounds__(256) void attn_kernel(const u16* __restrict__ qkv,
                                                   const u16* __restrict__ vt,
                                                   u16* __restrict__ ctx) {
  __shared__ __align__(16) u16 lds[128 * KLD];  // Q staging; then Ks(64 rows)||Vs(64 rows)
  u16* Ks = lds;
  u16* Vs = lds + 64 * KLD;

  int t = threadIdx.x;
  int wave = t >> 6, lane = t & 63, l31 = lane & 31, hi = lane >> 5;
  int qb = 15 - (int)blockIdx.x;  // long blocks first
  int h = blockIdx.y, b = blockIdx.z;
  int bh = b * 16 + h;
  int rowbase = b * 2048;
  int q0 = qb * 128;
  int qw = q0 + wave * 32;
  int q_lane = qw + l31;
  const float SCL = 0.18033688011112f;  // (1/8) * log2(e)

  // stage Q [128][64]
#pragma unroll
  for (int i = 0; i < 4; i++) {
    int idx = i * 256 + t; int r = idx >> 3, c8 = (idx & 7) * 8;
    *(uint4*)&lds[r * KLD + c8] =
        *(const uint4*)(qkv + (size_t)(rowbase + q0 + r) * 3072 + h * 64 + c8);
  }
  __syncthreads();
  // Q as B-operand frags: B[n=q=l31][k=hd=(hi)*8+j], k-step 16
  short8 qf[4];
#pragma unroll
  for (int ks = 0; ks < 4; ks++)
    qf[ks] = *(const short8*)&lds[(wave * 32 + l31) * KLD + ks * 16 + hi * 8];

  float m_run = -1e30f, l_run = 0.0f;
  f32x16 o[2];
  o[0] = (f32x16)0.0f; o[1] = (f32x16)0.0f;
  int hi4 = hi * 4;

  int ktmax = 2 * qb + 1;
  for (int kt = 0; kt <= ktmax; kt++) {
    __syncthreads();  // prev-iter frag reads done (and Q frags on iter 0)
#pragma unroll
    for (int i = 0; i < 2; i++) {
      int idx = i * 256 + t; int r = idx >> 3, c8 = (idx & 7) * 8;
      *(uint4*)&Ks[r * KLD + c8] =
          *(const uint4*)(qkv + (size_t)(rowbase + kt * 64 + r) * 3072 + 1024 + h * 64 + c8);
      *(uint4*)&Vs[r * KLD + c8] =
          *(const uint4*)(vt + ((size_t)bh * 64 + r) * 2048 + kt * 64 + c8);
    }
    __syncthreads();

    if (kt * 64 <= qw + 31) {  // wave-uniform: skip fully-masked tail tile
      // S^T = K Q^T : A = K[key][hd] from LDS, B = Q frags
      f32x16 st0 = (f32x16)0.0f, st1 = (f32x16)0.0f;
#pragma unroll
      for (int ks = 0; ks < 4; ks++) {
        short8 ka0 = *(const short8*)&Ks[(l31) * KLD + ks * 16 + hi * 8];
        short8 ka1 = *(const short8*)&Ks[(32 + l31) * KLD + ks * 16 + hi * 8];
        st0 = __builtin_amdgcn_mfma_f32_32x32x16_bf16(ka0, qf[ks], st0, 0, 0, 0);
        st1 = __builtin_amdgcn_mfma_f32_32x32x16_bf16(ka1, qf[ks], st1, 0, 0, 0);
      }
      // scale (+ causal mask only on boundary tiles); base-2 domain
      float sc[2][16];
      if (kt * 64 + 63 > qw) {
#pragma unroll
        for (int r = 0; r < 16; r++) {
          int key = kt * 64 + (r & 3) + 8 * (r >> 2) + hi4;
          sc[0][r] = (key <= q_lane) ? st0[r] * SCL : -1e30f;
          sc[1][r] = (key + 32 <= q_lane) ? st1[r] * SCL : -1e30f;
        }
      } else {
#pragma unroll
        for (int r = 0; r < 16; r++) { sc[0][r] = st0[r] * SCL; sc[1][r] = st1[r] * SCL; }
      }
      // per-lane online softmax (one q per lane; partner lane^32 has same q)
      float mo = -1e30f;
#pragma unroll
      for (int r = 0; r < 16; r++) mo = fmaxf(mo, fmaxf(sc[0][r], sc[1][r]));
      mo = fmaxf(mo, __shfl_xor(mo, 32));
      float mnew = fmaxf(m_run, mo);
      float alpha = __builtin_amdgcn_exp2f(m_run - mnew);
      m_run = mnew;
      float rs = 0.0f;
      unsigned pk[2][8];  // bf16 pairs, rows (2i,2i+1) of C-tile
#pragma unroll
      for (int km = 0; km < 2; km++)
#pragma unroll
        for (int i = 0; i < 8; i++) {
          float p0 = __builtin_amdgcn_exp2f(sc[km][2 * i] - mnew);
          float p1 = __builtin_amdgcn_exp2f(sc[km][2 * i + 1] - mnew);
          rs += p0 + p1;
          unsigned lo = (__float_as_uint(p0) + 0x8000u) >> 16;
          unsigned hi_ = (__float_as_uint(p1) + 0x8000u) & 0xffff0000u;
          pk[km][i] = lo | hi_;
        }
      rs += __shfl_xor(rs, 32);
      l_run = l_run * alpha + rs;
      o[0] = o[0] * alpha;
      o[1] = o[1] * alpha;
      // P -> B-operand frags in-register: B[n=q][k=key], k-step ks2
      short8 pf[4];
#pragma unroll
      for (int ks2 = 0; ks2 < 4; ks2++) {
        int km = ks2 >> 1, h4 = (ks2 & 1) * 4;
        unsigned A0 = pk[km][h4 + 0], A1 = pk[km][h4 + 1];
        unsigned B0 = pk[km][h4 + 2], B1 = pk[km][h4 + 3];
        unsigned tA0 = (unsigned)__shfl_xor((int)A0, 32);
        unsigned tA1 = (unsigned)__shfl_xor((int)A1, 32);
        unsigned tB0 = (unsigned)__shfl_xor((int)B0, 32);
        unsigned tB1 = (unsigned)__shfl_xor((int)B1, 32);
        union { unsigned u[4]; short8 s; } fr;
        fr.u[0] = hi ? tB0 : A0;
        fr.u[1] = hi ? tB1 : A1;
        fr.u[2] = hi ? B0 : tA0;
        fr.u[3] = hi ? B1 : tA1;
        pf[ks2] = fr.s;
      }
      // O^T += V^T P^T : A = V^T[hd][key] from LDS, B = P frags
#pragma unroll
      for (int am = 0; am < 2; am++)
#pragma unroll
        for (int ks2 = 0; ks2 < 4; ks2++) {
          short8 va = *(const short8*)&Vs[(am * 32 + l31) * KLD + ks2 * 16 + hi * 8];
          o[am] = __builtin_amdgcn_mfma_f32_32x32x16_bf16(va, pf[ks2], o[am], 0, 0, 0);
        }
    }
  }

  // epilogue: O^T reg (hd=(reg&3)+8*(reg>>2)+4hi+32am, q=l31) -> ctx[q][h*64+hd]
  float inv = 1.0f / l_run;
  size_t obase = (size_t)(rowbase + q_lane) * 1024 + h * 64;
#pragma unroll
  for (int am = 0; am < 2; am++)
#pragma unroll
    for (int k = 0; k < 4; k++) {
      ushort4 w;
      w.x = f2bf(o[am][4 * k + 0] * inv);
      w.y = f2bf(o[am][4 * k + 1] * inv);
      w.z = f2bf(o[am][4 * k + 2] * inv);
      w.w = f2bf(o[am][4 * k + 3] * inv);
      *(ushort4*)&ctx[obase + am * 32 + k * 8 + hi4] = w;
    }
}

// ---------------- launch ----------------
extern "C" void kernel_launch(void* const* d_in, const int* in_sizes, int n_in,
                              void* d_out, int out_size, void* d_ws, size_t ws_size,
                              hipStream_t stream) {
  const float* x      = (const float*)d_in[0];  // [4][2048][1024]
  const float* w_qkv  = (const float*)d_in[1];  // [1024][3072]
  const float* w_proj = (const float*)d_in[2];  // [1024][1024]
  float* out = (float*)d_out;                   // [4][2048][1024]

  char* ws = (char*)d_ws;
  u16* xb     = (u16*)(ws);                         // 16 MB (reused as ctx after gemm1)
  u16* wqkvT  = (u16*)(ws + 16u * 1024 * 1024);     //  6 MB  [3072][1024]
  u16* wprojT = (u16*)(ws + 22u * 1024 * 1024);     //  2 MB  [1024][1024]
  u16* qkv    = (u16*)(ws + 24u * 1024 * 1024);     // 48 MB  [8192][3072]
  u16* vt     = (u16*)(ws + 72u * 1024 * 1024);     // 16 MB  [4][16][64][2048]
  u16* ctx    = xb;                                 // alias: xb dead after gemm1

  cast_kernel<<<8192, 256, 0, stream>>>(x, xb, 2097152);
  tcast_kernel<<<dim3(96, 32), 256, 0, stream>>>(w_qkv, wqkvT, 1024, 3072);
  tcast_kernel<<<dim3(32, 32), 256, 0, stream>>>(w_proj, wprojT, 1024, 1024);

  gemm_bt<u16><<<dim3(24, 64), 256, 0, stream>>>(xb, wqkvT, qkv, 8192, 3072, 1024);
  vtrans<<<dim3(32, 16, 4), 256, 0, stream>>>(qkv, vt);
  attn_kernel<<<dim3(16, 16, 4), 256, 0, stream>>>(qkv, vt, ctx);
  gemm_bt<float><<<dim3(8, 64), 256, 0, stream>>>(ctx, wprojT, out, 8192, 1024, 1024);
}

// Round 3
// 332.594 us; speedup vs baseline: 1.5902x; 1.0403x over previous
//
#include <hip/hip_runtime.h>
#include <hip/hip_bf16.h>

typedef unsigned short u16;
typedef __attribute__((ext_vector_type(8))) short short8;
typedef __attribute__((ext_vector_type(4))) float f32x4;
typedef __attribute__((ext_vector_type(16))) float f32x16;

__device__ inline u16 f2bf(float f) {
  unsigned u = __float_as_uint(f);
  u += 0x7fffu + ((u >> 16) & 1u);   // round-to-nearest-even
  return (u16)(u >> 16);
}

// ---------------- cast fp32 -> bf16 (vectorized x4) ----------------
__global__ __launch_bounds__(256) void cast_kernel(const float* __restrict__ in,
                                                   u16* __restrict__ out, int n4) {
  int i = blockIdx.x * 256 + threadIdx.x;
  if (i >= n4) return;
  float4 v = ((const float4*)in)[i];
  ushort4 o;
  o.x = f2bf(v.x); o.y = f2bf(v.y); o.z = f2bf(v.z); o.w = f2bf(v.w);
  ((ushort4*)out)[i] = o;
}

// ---------------- transpose-cast: fp32 [K][N] -> bf16 [N][K] ----------------
__global__ __launch_bounds__(256) void tcast_kernel(const float* __restrict__ in,
                                                    u16* __restrict__ out, int K, int N) {
  __shared__ float tile[32][33];
  int bx = blockIdx.x * 32;  // N offset
  int by = blockIdx.y * 32;  // K offset
  int tx = threadIdx.x & 31, ty = threadIdx.x >> 5;
#pragma unroll
  for (int i = 0; i < 4; i++) {
    int r = ty + i * 8;
    tile[r][tx] = in[(size_t)(by + r) * N + bx + tx];
  }
  __syncthreads();
#pragma unroll
  for (int i = 0; i < 4; i++) {
    int r = ty + i * 8;
    out[(size_t)(bx + r) * K + by + tx] = f2bf(tile[tx][r]);
  }
}

// ---------------- V transpose: qkv V-part [s][hd] -> vt [b][h][hd][S] ----------------
__global__ __launch_bounds__(256) void vtrans(const u16* __restrict__ qkv, u16* __restrict__ vt) {
  __shared__ __align__(16) u16 tile[64 * 72];
  int t = threadIdx.x;
  int s0 = blockIdx.x * 64, h = blockIdx.y, b = blockIdx.z;
  int bh = b * 16 + h;
#pragma unroll
  for (int i = 0; i < 2; i++) {
    int idx = i * 256 + t; int r = idx >> 3, c8 = (idx & 7) * 8;
    *(uint4*)&tile[r * 72 + c8] =
        *(const uint4*)(qkv + (size_t)(b * 2048 + s0 + r) * 3072 + 2048 + h * 64 + c8);
  }
  __syncthreads();
#pragma unroll
  for (int i = 0; i < 2; i++) {
    int idx = i * 256 + t; int hd = idx >> 3, c8 = (idx & 7) * 8;
    union { ushort s[8]; uint4 u; } pkv;
#pragma unroll
    for (int j = 0; j < 8; j++) pkv.s[j] = tile[(c8 + j) * 72 + hd];
    *(uint4*)(vt + ((size_t)bh * 64 + hd) * 2048 + s0 + c8) = pkv.u;
  }
}

// ---------------- GEMM: C[M][N] = A[M][K] * Bt[N][K]^T, m97-style ----------------
// 128x128 tile, BK=32, unpadded LDS [128][32], global_load_lds width=16.
__device__ inline void cstore(float* p, float v) { *p = v; }
__device__ inline void cstore(u16* p, float v) { *p = f2bf(v); }

template <typename OutT>
__global__ __launch_bounds__(256) void gemm_bt(const u16* __restrict__ A,
                                               const u16* __restrict__ Bt,
                                               OutT* __restrict__ Co,
                                               int M, int N, int K) {
  __shared__ __align__(16) u16 As[128 * 32];
  __shared__ __align__(16) u16 Bs[128 * 32];
  int t = threadIdx.x;
  int wave = t >> 6, lane = t & 63, l15 = lane & 15, quad = lane >> 4;
  int bn = blockIdx.x * 128, bm = blockIdx.y * 128;
  int wm = (wave >> 1) * 64, wn = (wave & 1) * 64;

  f32x4 acc[4][4];
#pragma unroll
  for (int i = 0; i < 4; i++)
#pragma unroll
    for (int j = 0; j < 4; j++) acc[i][j] = (f32x4)0.0f;

  int srow = wave * 16 + (lane >> 2);
  int scol = (lane & 3) * 8;
  const u16* ga0 = A  + (size_t)(bm + srow) * K + scol;
  const u16* ga1 = A  + (size_t)(bm + 64 + srow) * K + scol;
  const u16* gb0 = Bt + (size_t)(bn + srow) * K + scol;
  const u16* gb1 = Bt + (size_t)(bn + 64 + srow) * K + scol;
  u16* lA0 = As + wave * 512;
  u16* lA1 = As + 2048 + wave * 512;
  u16* lB0 = Bs + wave * 512;
  u16* lB1 = Bs + 2048 + wave * 512;

  for (int k0 = 0; k0 < K; k0 += 32) {
    __syncthreads();
    __builtin_amdgcn_global_load_lds((const __attribute__((address_space(1))) unsigned*)(ga0 + k0),
                                     (__attribute__((address_space(3))) unsigned*)lA0, 16, 0, 0);
    __builtin_amdgcn_global_load_lds((const __attribute__((address_space(1))) unsigned*)(ga1 + k0),
                                     (__attribute__((address_space(3))) unsigned*)lA1, 16, 0, 0);
    __builtin_amdgcn_global_load_lds((const __attribute__((address_space(1))) unsigned*)(gb0 + k0),
                                     (__attribute__((address_space(3))) unsigned*)lB0, 16, 0, 0);
    __builtin_amdgcn_global_load_lds((const __attribute__((address_space(1))) unsigned*)(gb1 + k0),
                                     (__attribute__((address_space(3))) unsigned*)lB1, 16, 0, 0);
    __syncthreads();

    short8 a[4], b[4];
#pragma unroll
    for (int mt = 0; mt < 4; mt++)
      a[mt] = *(const short8*)(&As[(wm + mt * 16 + l15) * 32 + quad * 8]);
#pragma unroll
    for (int nt = 0; nt < 4; nt++)
      b[nt] = *(const short8*)(&Bs[(wn + nt * 16 + l15) * 32 + quad * 8]);
#pragma unroll
    for (int mt = 0; mt < 4; mt++)
#pragma unroll
      for (int nt = 0; nt < 4; nt++)
        acc[mt][nt] = __builtin_amdgcn_mfma_f32_16x16x32_bf16(a[mt], b[nt], acc[mt][nt], 0, 0, 0);
  }

#pragma unroll
  for (int mt = 0; mt < 4; mt++)
#pragma unroll
    for (int nt = 0; nt < 4; nt++)
#pragma unroll
      for (int r = 0; r < 4; r++) {
        int row = bm + wm + mt * 16 + quad * 4 + r;
        int col = bn + wn + nt * 16 + l15;
        cstore(&Co[(size_t)row * N + col], acc[mt][nt][r]);
      }
}

// ---------------- flash attention: barrier-free, no LDS ----------------
// One wave owns one 32-query strip. S^T = K*Q^T via 32x32x16 (C/D col=q=lane&31,
// row=(reg&3)+8*(reg>>2)+4*(lane>>5), m74/m101-verified) => per-lane softmax state.
// K and V^T A-fragments read DIRECTLY from global (16B/lane); Q frags cached in regs.
// Block i carries strips {i, 31-i, 32+i, 63-i} (uniform work), rotated over waves.
// XCD swizzle: bh == xcd (mod 8) so each XCD's K/V working set fits its 4MB L2.
__global__ __launch_bounds__(256, 4) void attn_kernel(const u16* __restrict__ qkv,
                                                      const u16* __restrict__ vt,
                                                      u16* __restrict__ ctx) {
  int t = threadIdx.x;
  int wave = t >> 6, lane = t & 63, l31 = lane & 31, hi = lane >> 5;
  int lid = (int)blockIdx.x + 16 * (int)blockIdx.y + 256 * (int)blockIdx.z;
  int xcd = lid & 7, slot = lid >> 3;
  int bh = xcd + 8 * (slot & 7);
  int i = slot >> 3;
  int b = bh >> 4, h = bh & 15;
  int ww = (wave + i) & 3;
  int strip = (ww == 0) ? i : (ww == 1) ? 31 - i : (ww == 2) ? 32 + i : 63 - i;
  int rowbase = b * 2048;
  int q0 = strip * 32;
  int q_lane = q0 + l31;
  const float SCL = 0.18033688011112f;  // (1/8) * log2(e)

  // Q as B-operand frags, direct from global: B[n=q=l31][k=hd], k-step 16
  const u16* qp = qkv + (size_t)(rowbase + q_lane) * 3072 + h * 64 + hi * 8;
  short8 qf[4];
#pragma unroll
  for (int ks = 0; ks < 4; ks++) qf[ks] = *(const short8*)(qp + ks * 16);

  // bases: K rows l31 / l31+32 advance 64 rows per kt; V^T cols advance 64 per kt
  const u16* kp = qkv + (size_t)(rowbase + l31) * 3072 + 1024 + h * 64 + hi * 8;
  const u16* vp = vt + ((size_t)bh * 64 + l31) * 2048 + hi * 8;

  float m_run = -1e30f, l_run = 0.0f;
  f32x16 o[2];
  o[0] = (f32x16)0.0f; o[1] = (f32x16)0.0f;
  int hi4 = hi * 4;
  int ktmax = (q0 + 31) >> 6;

  for (int kt = 0; kt <= ktmax; kt++) {
    const u16* kb = kp + (size_t)kt * (64 * 3072);
    const u16* vb = vp + kt * 64;

    // S^T = K Q^T : A = K[key][hd] direct from global
    f32x16 st0 = (f32x16)0.0f, st1 = (f32x16)0.0f;
#pragma unroll
    for (int ks = 0; ks < 4; ks++) {
      short8 ka0 = *(const short8*)(kb + ks * 16);
      short8 ka1 = *(const short8*)(kb + 32 * 3072 + ks * 16);
      st0 = __builtin_amdgcn_mfma_f32_32x32x16_bf16(ka0, qf[ks], st0, 0, 0, 0);
      st1 = __builtin_amdgcn_mfma_f32_32x32x16_bf16(ka1, qf[ks], st1, 0, 0, 0);
    }

    // scale (+ causal mask only on the boundary tile); base-2 domain
    float sc[2][16];
    if (kt == ktmax) {
#pragma unroll
      for (int r = 0; r < 16; r++) {
        int key = kt * 64 + (r & 3) + 8 * (r >> 2) + hi4;
        sc[0][r] = (key <= q_lane) ? st0[r] * SCL : -1e30f;
        sc[1][r] = (key + 32 <= q_lane) ? st1[r] * SCL : -1e30f;
      }
    } else {
#pragma unroll
      for (int r = 0; r < 16; r++) { sc[0][r] = st0[r] * SCL; sc[1][r] = st1[r] * SCL; }
    }

    // per-lane online softmax (partner lane^32 holds same q, other key half)
    float mo = -1e30f;
#pragma unroll
    for (int r = 0; r < 16; r++) mo = fmaxf(mo, fmaxf(sc[0][r], sc[1][r]));
    mo = fmaxf(mo, __shfl_xor(mo, 32));
    float mnew = fmaxf(m_run, mo);
    float alpha = __builtin_amdgcn_exp2f(m_run - mnew);
    m_run = mnew;
    float rs = 0.0f;
    unsigned pk[2][8];
#pragma unroll
    for (int km = 0; km < 2; km++)
#pragma unroll
      for (int ii = 0; ii < 8; ii++) {
        float p0 = __builtin_amdgcn_exp2f(sc[km][2 * ii] - mnew);
        float p1 = __builtin_amdgcn_exp2f(sc[km][2 * ii + 1] - mnew);
        rs += p0 + p1;
        unsigned lo = (__float_as_uint(p0) + 0x8000u) >> 16;
        unsigned hi_ = (__float_as_uint(p1) + 0x8000u) & 0xffff0000u;
        pk[km][ii] = lo | hi_;
      }
    rs += __shfl_xor(rs, 32);
    l_run = l_run * alpha + rs;
    o[0] = o[0] * alpha;
    o[1] = o[1] * alpha;

    // P -> B-operand frags in-register (verified reroute via shfl_xor 32)
    short8 pf[4];
#pragma unroll
    for (int ks2 = 0; ks2 < 4; ks2++) {
      int km = ks2 >> 1, h4 = (ks2 & 1) * 4;
      unsigned A0 = pk[km][h4 + 0], A1 = pk[km][h4 + 1];
      unsigned B0 = pk[km][h4 + 2], B1 = pk[km][h4 + 3];
      unsigned tA0 = (unsigned)__shfl_xor((int)A0, 32);
      unsigned tA1 = (unsigned)__shfl_xor((int)A1, 32);
      unsigned tB0 = (unsigned)__shfl_xor((int)B0, 32);
      unsigned tB1 = (unsigned)__shfl_xor((int)B1, 32);
      union { unsigned u[4]; short8 s; } fr;
      fr.u[0] = hi ? tB0 : A0;
      fr.u[1] = hi ? tB1 : A1;
      fr.u[2] = hi ? B0 : tA0;
      fr.u[3] = hi ? B1 : tA1;
      pf[ks2] = fr.s;
    }

    // O^T += V^T P^T : A = V^T[hd][key] direct from global
#pragma unroll
    for (int am = 0; am < 2; am++)
#pragma unroll
      for (int ks2 = 0; ks2 < 4; ks2++) {
        short8 va = *(const short8*)(vb + am * (32 * 2048) + ks2 * 16);
        o[am] = __builtin_amdgcn_mfma_f32_32x32x16_bf16(va, pf[ks2], o[am], 0, 0, 0);
      }
  }

  // epilogue: O^T reg (hd=(reg&3)+8*(reg>>2)+4hi+32am, q=l31) -> ctx[q][h*64+hd]
  float inv = 1.0f / l_run;
  size_t obase = (size_t)(rowbase + q_lane) * 1024 + h * 64;
#pragma unroll
  for (int am = 0; am < 2; am++)
#pragma unroll
    for (int k = 0; k < 4; k++) {
      ushort4 w;
      w.x = f2bf(o[am][4 * k + 0] * inv);
      w.y = f2bf(o[am][4 * k + 1] * inv);
      w.z = f2bf(o[am][4 * k + 2] * inv);
      w.w = f2bf(o[am][4 * k + 3] * inv);
      *(ushort4*)&ctx[obase + am * 32 + k * 8 + hi4] = w;
    }
}

// ---------------- launch ----------------
extern "C" void kernel_launch(void* const* d_in, const int* in_sizes, int n_in,
                              void* d_out, int out_size, void* d_ws, size_t ws_size,
                              hipStream_t stream) {
  const float* x      = (const float*)d_in[0];  // [4][2048][1024]
  const float* w_qkv  = (const float*)d_in[1];  // [1024][3072]
  const float* w_proj = (const float*)d_in[2];  // [1024][1024]
  float* out = (float*)d_out;                   // [4][2048][1024]

  char* ws = (char*)d_ws;
  u16* xb     = (u16*)(ws);                         // 16 MB (reused as ctx after gemm1)
  u16* wqkvT  = (u16*)(ws + 16u * 1024 * 1024);     //  6 MB  [3072][1024]
  u16* wprojT = (u16*)(ws + 22u * 1024 * 1024);     //  2 MB  [1024][1024]
  u16* qkv    = (u16*)(ws + 24u * 1024 * 1024);     // 48 MB  [8192][3072]
  u16* vt     = (u16*)(ws + 72u * 1024 * 1024);     // 16 MB  [4][16][64][2048]
  u16* ctx    = xb;                                 // alias: xb dead after gemm1

  cast_kernel<<<8192, 256, 0, stream>>>(x, xb, 2097152);
  tcast_kernel<<<dim3(96, 32), 256, 0, stream>>>(w_qkv, wqkvT, 1024, 3072);
  tcast_kernel<<<dim3(32, 32), 256, 0, stream>>>(w_proj, wprojT, 1024, 1024);

  gemm_bt<u16><<<dim3(24, 64), 256, 0, stream>>>(xb, wqkvT, qkv, 8192, 3072, 1024);
  vtrans<<<dim3(32, 16, 4), 256, 0, stream>>>(qkv, vt);
  attn_kernel<<<dim3(16, 16, 4), 256, 0, stream>>>(qkv, vt, ctx);
  gemm_bt<float><<<dim3(8, 64), 256, 0, stream>>>(ctx, wprojT, out, 8192, 1024, 1024);
}